// Round 9
// baseline (4057.504 us; speedup 1.0000x reference)
//
#include <hip/hip_runtime.h>
#include <hip/hip_bf16.h>

// Encoder: e = embed[x]; q = LSTM_q(e); k = LSTM_k(e); A = q @ k^T (per batch)
// B=32, T=512, D=512, NUM_TOKENS=14.
//
// R9: wave-autonomous persistent recurrence (flat, no XCD pinning).
// 64 WGs (32 per LSTM, 16 dims each), 256 thr. Each wave owns
// (batch-half mt, dim-half rt): polls tagged h words (bf16<<16 | t+1, proven
// R7) for its 16 batches directly into registers, MFMAs 2 tiles (i/f rows and
// g/o rows of its 8 dims), gathers the cross-gate values with one
// __shfl_xor(8). NO __syncthreads and NO LDS writes in the step loop; waves
// drift freely, synced only by data tags. 2-phase hbf safety proof as R7.

#define TB 32
#define TT 512
#define TD 512
#define NTOK 14

typedef __attribute__((ext_vector_type(8))) short short8;
typedef __attribute__((ext_vector_type(4))) float f32x4;
typedef __attribute__((ext_vector_type(4))) unsigned int u32x4;

__device__ __forceinline__ float fsigmoid(float v) { return 1.f / (1.f + __expf(-v)); }
__device__ __forceinline__ float ftanh(float v) {
    float a = fabsf(v);
    float e = __expf(-2.f * a);
    float r = (1.f - e) / (1.f + e);
    return copysignf(r, v);
}
__device__ __forceinline__ unsigned int f2bf(float f) {
    __hip_bfloat16 h = __float2bfloat16(f);
    return (unsigned int)__builtin_bit_cast(unsigned short, h);
}

// device-coherent 16B load (bypass L1/L2 -> reads the coherent point)
__device__ __forceinline__ u32x4 load16_coh(const unsigned int* p) {
    u32x4 r;
    asm volatile("global_load_dwordx4 %0, %1, off sc0 sc1" : "=v"(r) : "v"(p));
    return r;
}
// device-coherent 4B store (write-through; fire-and-forget)
__device__ __forceinline__ void store4_coh(unsigned int* p, unsigned int v) {
    asm volatile("global_store_dword %0, %1, off sc0 sc1" :: "v"(p), "v"(v) : "memory");
}

// ---- pre_tab[l][tok][2048] = embed[tok] @ W_ih_l^T + b_ih_l + b_hh_l ----
__global__ __launch_bounds__(256) void pre_tab_kernel(
    const float* __restrict__ embed,
    const float* __restrict__ Wih_q, const float* __restrict__ bih_q, const float* __restrict__ bhh_q,
    const float* __restrict__ Wih_k, const float* __restrict__ bih_k, const float* __restrict__ bhh_k,
    float* __restrict__ pre)
{
    int idx = blockIdx.x * 256 + threadIdx.x;   // 2*14*2048 = 57344 exactly
    int l = idx / (NTOK * 4 * TD);
    int r = idx % (NTOK * 4 * TD);
    int tok = r / (4 * TD), j = r % (4 * TD);
    const float* Wih = l ? Wih_k : Wih_q;
    float acc = l ? (bih_k[j] + bhh_k[j]) : (bih_q[j] + bhh_q[j]);
    const float4* e4 = (const float4*)(embed + (size_t)tok * TD);
    const float4* w4 = (const float4*)(Wih + (size_t)j * TD);
    for (int t2 = 0; t2 < TD / 4; ++t2) {
        float4 e = e4[t2], w = w4[t2];
        acc += e.x * w.x + e.y * w.y + e.z * w.z + e.w * w.w;
    }
    pre[idx] = acc;
}

__global__ __launch_bounds__(256) void init_hbf(unsigned int* hbf) {
    hbf[blockIdx.x * 256 + threadIdx.x] = 0;    // 2*2*32*512 = 65536; tag 0 never matches
}

// ---- persistent LSTM: 64 WGs (wg>>5 = lstm l, (wg&31)*16 = dim base) ----
__global__ __launch_bounds__(256) void lstm_persist(
    const float* __restrict__ Whh_q, const float* __restrict__ Whh_k,
    const float* __restrict__ pre,
    const int* __restrict__ x,
    float* __restrict__ qout, float* __restrict__ kout,
    unsigned int* __restrict__ hbf)
{
    // w_lds row r (r = rt*32 + tt*16 + n): W_hh row gate*512 + d0g + rt*8 + (n&7),
    // gate = tt*2 + (n>>3). 16B chunks XOR-swizzled by row (conflict-free reads).
    __shared__ unsigned short w_lds[64][512];   // 64 KB
    __shared__ unsigned char  x_lds[TB * TT];   // 16 KB
    __shared__ float          pre_lds[NTOK][64];// [tok][gate*16 + rt*8 + dd]

    int wg  = blockIdx.x;
    int l   = wg >> 5;
    int d0g = (wg & 31) << 4;                   // 16 dims per WG
    int tid = threadIdx.x;
    int lane = tid & 63;
    int wv = tid >> 6;
    int mt = wv & 1;                            // batch half (b = mt*16 ..)
    int rt = wv >> 1;                           // dim half (dims d0g+rt*8 ..)

    const float* Whh = l ? Whh_k : Whh_q;
    float* hist = l ? kout : qout;

    // ---- stage W slice: 64 rows, 4 threads/row, 16 chunks each ----
    {
        int r = tid >> 2;                       // 0..63
        int rtr = r >> 5, ttr = (r >> 4) & 1, n = r & 15;
        int gate = ttr * 2 + (n >> 3);
        const float* src = Whh + (size_t)(gate * TD + d0g + rtr * 8 + (n & 7)) * TD;
#pragma unroll
        for (int i = 0; i < 16; ++i) {
            int c = (tid & 3) + 4 * i;          // chunk 0..63 (8 bf16 each)
            float4 a = ((const float4*)src)[c * 2];
            float4 b4 = ((const float4*)src)[c * 2 + 1];
            unsigned short* dst = &w_lds[r][(c ^ (r & 7)) * 8];
            dst[0] = (unsigned short)f2bf(a.x); dst[1] = (unsigned short)f2bf(a.y);
            dst[2] = (unsigned short)f2bf(a.z); dst[3] = (unsigned short)f2bf(a.w);
            dst[4] = (unsigned short)f2bf(b4.x); dst[5] = (unsigned short)f2bf(b4.y);
            dst[6] = (unsigned short)f2bf(b4.z); dst[7] = (unsigned short)f2bf(b4.w);
        }
    }
    for (int i = tid; i < TB * TT; i += 256) x_lds[i] = (unsigned char)x[i];
    for (int i = tid; i < NTOK * 64; i += 256) {
        int tok = i >> 6, j = i & 63;           // j = gate*16 + rtdd
        pre_lds[tok][j] = pre[((size_t)l * NTOK + tok) * (4 * TD) + (j >> 4) * TD + d0g + (j & 15)];
    }
    __syncthreads();                            // only barrier in the kernel

    int ba = mt * 16 + (lane & 15);             // this lane's A-frag batch
    int r0 = rt * 32 + (lane & 15);             // tile0 (i|f) w_lds row
    int r1 = r0 + 16;                           // tile1 (g|o) w_lds row
    float cst[4] = {0.f, 0.f, 0.f, 0.f};        // c-state (lanes with col<8)

    for (int t = 0; t < TT; ++t) {
        // ---- poll-load h(t-1) (tagged u32) straight into registers ----
        short8 afr[16];
        if (t > 0) {
            const unsigned int e = (unsigned int)t;
            const unsigned int* hb = hbf
                + (size_t)((((t - 1) & 1) * 2 + l) * TB + ba) * TD + ((lane >> 4) * 8);
            u32x4 A0[16], B0[16];
#pragma unroll
            for (int kk = 0; kk < 16; ++kk) {
                A0[kk] = load16_coh(hb + kk * 32);
                B0[kk] = load16_coh(hb + kk * 32 + 4);
            }
            unsigned int st = 0xffffu;
            for (;;) {
                asm volatile("s_waitcnt vmcnt(0)" ::: "memory");
                __builtin_amdgcn_sched_barrier(0);
                unsigned int ns = 0;
#pragma unroll
                for (int kk = 0; kk < 16; ++kk) if (st & (1u << kk)) {
                    unsigned int bad =
                        ((A0[kk].x ^ e) | (A0[kk].y ^ e) | (A0[kk].z ^ e) | (A0[kk].w ^ e) |
                         (B0[kk].x ^ e) | (B0[kk].y ^ e) | (B0[kk].z ^ e) | (B0[kk].w ^ e)) & 0xffffu;
                    if (bad) ns |= 1u << kk;
                }
                st = ns;
                if (!__any(st != 0)) break;
#pragma unroll
                for (int kk = 0; kk < 16; ++kk) if (st & (1u << kk)) {
                    A0[kk] = load16_coh(hb + kk * 32);
                    B0[kk] = load16_coh(hb + kk * 32 + 4);
                }
            }
#pragma unroll
            for (int kk = 0; kk < 16; ++kk) {
                u32x4 g;
                g.x = (A0[kk].x >> 16) | (A0[kk].y & 0xffff0000u);
                g.y = (A0[kk].z >> 16) | (A0[kk].w & 0xffff0000u);
                g.z = (B0[kk].x >> 16) | (B0[kk].y & 0xffff0000u);
                g.w = (B0[kk].z >> 16) | (B0[kk].w & 0xffff0000u);
                afr[kk] = __builtin_bit_cast(short8, g);
            }
        }

        // ---- MFMA: 2 tiles (i/f rows, g/o rows), K=512, all in-wave ----
        f32x4 acc0 = {0.f, 0.f, 0.f, 0.f};
        f32x4 acc1 = {0.f, 0.f, 0.f, 0.f};
        if (t > 0) {
#pragma unroll
            for (int kk = 0; kk < 16; ++kk) {
                int c = kk * 4 + (lane >> 4);
                short8 b0 = *(const short8*)&w_lds[r0][(c ^ (r0 & 7)) * 8];
                short8 b1 = *(const short8*)&w_lds[r1][(c ^ (r1 & 7)) * 8];
                acc0 = __builtin_amdgcn_mfma_f32_16x16x32_bf16(afr[kk], b0, acc0, 0, 0, 0);
                acc1 = __builtin_amdgcn_mfma_f32_16x16x32_bf16(afr[kk], b1, acc1, 0, 0, 0);
            }
        }

        // ---- tail: cross-gate gather via shfl_xor(8), all in-wave ----
        // C/D: col = lane&15 (tile row: cols 0-7 = gates i|g dims dd, 8-15 = f|o),
        //      row = (lane>>4)*4 + r2 (batch within half)
        float fF[4], fO[4];
#pragma unroll
        for (int r2 = 0; r2 < 4; ++r2) {
            fF[r2] = __shfl_xor(acc0[r2], 8);
            fO[r2] = __shfl_xor(acc1[r2], 8);
        }
        if ((lane & 15) < 8) {
            int dd = lane & 15;
            int rtdd = rt * 8 + dd;
            int dG = d0g + rtdd;
#pragma unroll
            for (int r2 = 0; r2 < 4; ++r2) {
                int b = mt * 16 + ((lane >> 4) << 2) + r2;
                int tok = x_lds[b * TT + t];
                float gi = acc0[r2] + pre_lds[tok][rtdd];
                float gf = fF[r2]   + pre_lds[tok][16 + rtdd];
                float gg = acc1[r2] + pre_lds[tok][32 + rtdd];
                float go = fO[r2]   + pre_lds[tok][48 + rtdd];
                float i_ = fsigmoid(gi), f_ = fsigmoid(gf), g_ = ftanh(gg), o_ = fsigmoid(go);
                cst[r2] = f_ * cst[r2] + i_ * g_;
                float h = o_ * ftanh(cst[r2]);
                hist[((size_t)b * TT + t) * TD + dG] = h;     // plain cached f32
                store4_coh(hbf + (size_t)(((t & 1) * 2 + l) * TB + b) * TD + dG,
                           (f2bf(h) << 16) | (unsigned int)(t + 1));
            }
        }
        // no barrier, no drain: consumers poll the tagged words
    }
}

// ---- A[b] = q[b] @ k[b]^T, f32, 64x64 tile / WG, 4x4 per thread ----
__global__ __launch_bounds__(256) void qk_gemm(
    const float* __restrict__ q, const float* __restrict__ k, float* __restrict__ A)
{
    __shared__ float qs[64][68];
    __shared__ float ks[64][68];
    int b = blockIdx.y;
    int t0 = (blockIdx.x >> 3) * 64;
    int s0 = (blockIdx.x & 7) * 64;
    const float* qb = q + (size_t)b * TT * TD;
    const float* kb = k + (size_t)b * TT * TD;
    int tid = threadIdx.x;
    int ty = tid >> 4, tx = tid & 15;
    float accr[4][4] = {};
    for (int k0 = 0; k0 < TD; k0 += 64) {
        for (int i = tid; i < 64 * 16; i += 256) {
            int r = i >> 4, c4 = i & 15;
            ((float4*)&qs[r][0])[c4] = ((const float4*)(qb + (size_t)(t0 + r) * TD + k0))[c4];
            ((float4*)&ks[r][0])[c4] = ((const float4*)(kb + (size_t)(s0 + r) * TD + k0))[c4];
        }
        __syncthreads();
#pragma unroll 4
        for (int kk = 0; kk < 64; kk += 4) {
            float4 qv[4], kv[4];
#pragma unroll
            for (int i = 0; i < 4; ++i) qv[i] = *(const float4*)&qs[ty * 4 + i][kk];
#pragma unroll
            for (int j = 0; j < 4; ++j) kv[j] = *(const float4*)&ks[tx * 4 + j][kk];
#pragma unroll
            for (int i = 0; i < 4; ++i)
#pragma unroll
                for (int j = 0; j < 4; ++j)
                    accr[i][j] += qv[i].x * kv[j].x + qv[i].y * kv[j].y
                                + qv[i].z * kv[j].z + qv[i].w * kv[j].w;
        }
        __syncthreads();
    }
    for (int i = 0; i < 4; ++i)
        for (int j = 0; j < 4; ++j)
            A[(size_t)b * TT * TT + (size_t)(t0 + ty * 4 + i) * TT + (s0 + tx * 4 + j)] = accr[i][j];
}

extern "C" void kernel_launch(void* const* d_in, const int* in_sizes, int n_in,
                              void* d_out, int out_size, void* d_ws, size_t ws_size,
                              hipStream_t stream)
{
    const int*   x      = (const int*)d_in[0];
    const float* embed  = (const float*)d_in[1];
    const float* Wih_q  = (const float*)d_in[2];
    const float* Whh_q  = (const float*)d_in[3];
    const float* bih_q  = (const float*)d_in[4];
    const float* bhh_q  = (const float*)d_in[5];
    const float* Wih_k  = (const float*)d_in[6];
    const float* Whh_k  = (const float*)d_in[7];
    const float* bih_k  = (const float*)d_in[8];
    const float* bhh_k  = (const float*)d_in[9];

    float* ws   = (float*)d_ws;
    float* q    = ws;                                   // 8388608 f
    float* kbuf = q + (size_t)TB * TT * TD;             // 8388608 f
    float* pre  = kbuf + (size_t)TB * TT * TD;          // 57344 f
    unsigned int* hbf = (unsigned int*)(pre + 2 * NTOK * 4 * TD);  // 65536 u32

    init_hbf<<<256, 256, 0, stream>>>(hbf);
    pre_tab_kernel<<<224, 256, 0, stream>>>(embed, Wih_q, bih_q, bhh_q,
                                            Wih_k, bih_k, bhh_k, pre);
    lstm_persist<<<64, 256, 0, stream>>>(Whh_q, Whh_k, pre, x, q, kbuf, hbf);
    dim3 g(64, 32);
    qk_gemm<<<g, 256, 0, stream>>>(q, kbuf, (float*)d_out);
}

// Round 10
// 2422.343 us; speedup vs baseline: 1.6750x; 1.6750x over previous
//
#include <hip/hip_runtime.h>
#include <hip/hip_bf16.h>

// Encoder: e = embed[x]; q = LSTM_q(e); k = LSTM_k(e); A = q @ k^T (per batch)
// B=32, T=512, D=512, NUM_TOKENS=14.
//
// R10: G=32 WGs/LSTM (64 total, 512 thr), 16 dims/WG, W in LDS (64 KB),
// h staged once/WG (tagless bf16, 2 MB/step total L3 reads vs R6's 8 MB).
// A/B batch-group pipelining: groups (b 0-15) and (b 16-31) alternate within
// each step; group X's store->visible->poll latency hides under group Y's
// stage+MFMA+tail. Sync = R6's proven per-WG flag protocol (drain -> barrier
// -> one flag store; no fences, no atomics). 2-phase hbf per group (R7 proof).

#define TB 32
#define TT 512
#define TD 512
#define NTOK 14

typedef __attribute__((ext_vector_type(8))) short short8;
typedef __attribute__((ext_vector_type(4))) float f32x4;

__device__ __forceinline__ float fsigmoid(float v) { return 1.f / (1.f + __expf(-v)); }
__device__ __forceinline__ float ftanh(float v) {
    float a = fabsf(v);
    float e = __expf(-2.f * a);
    float r = (1.f - e) / (1.f + e);
    return copysignf(r, v);
}
__device__ __forceinline__ unsigned int f2bf(float f) {
    __hip_bfloat16 h = __float2bfloat16(f);
    return (unsigned int)__builtin_bit_cast(unsigned short, h);
}

// device-coherent 16B load (L1/L2 bypass -> reads coherent point)
__device__ __forceinline__ short8 load16_coh(const unsigned short* p) {
    short8 r;
    asm volatile("global_load_dwordx4 %0, %1, off sc0 sc1" : "=v"(r) : "v"(p));
    return r;
}
// device-coherent 2B/4B stores (write-through, fire-and-forget)
__device__ __forceinline__ void store2_coh(unsigned short* p, unsigned int v) {
    asm volatile("global_store_short %0, %1, off sc0 sc1" :: "v"(p), "v"(v) : "memory");
}
__device__ __forceinline__ void store4_coh(unsigned int* p, unsigned int v) {
    asm volatile("global_store_dword %0, %1, off sc0 sc1" :: "v"(p), "v"(v) : "memory");
}
// coherent dword load with completed wait (for flag polling)
__device__ __forceinline__ unsigned int load4_coh(const unsigned int* p) {
    unsigned int r;
    asm volatile("global_load_dword %0, %1, off sc0 sc1\n\ts_waitcnt vmcnt(0)"
                 : "=v"(r) : "v"(p) : "memory");
    return r;
}

// ---- pre_tab[l][tok][2048] = embed[tok] @ W_ih_l^T + b_ih_l + b_hh_l ----
__global__ __launch_bounds__(256) void pre_tab_kernel(
    const float* __restrict__ embed,
    const float* __restrict__ Wih_q, const float* __restrict__ bih_q, const float* __restrict__ bhh_q,
    const float* __restrict__ Wih_k, const float* __restrict__ bih_k, const float* __restrict__ bhh_k,
    float* __restrict__ pre)
{
    int idx = blockIdx.x * 256 + threadIdx.x;   // 2*14*2048 = 57344 exactly
    int l = idx / (NTOK * 4 * TD);
    int r = idx % (NTOK * 4 * TD);
    int tok = r / (4 * TD), j = r % (4 * TD);
    const float* Wih = l ? Wih_k : Wih_q;
    float acc = l ? (bih_k[j] + bhh_k[j]) : (bih_q[j] + bhh_q[j]);
    const float4* e4 = (const float4*)(embed + (size_t)tok * TD);
    const float4* w4 = (const float4*)(Wih + (size_t)j * TD);
    for (int t2 = 0; t2 < TD / 4; ++t2) {
        float4 e = e4[t2], w = w4[t2];
        acc += e.x * w.x + e.y * w.y + e.z * w.z + e.w * w.w;
    }
    pre[idx] = acc;
}

__global__ void init_flags(unsigned int* flags) { flags[threadIdx.x] = 0; }

// ---- persistent LSTM: 64 WGs (wg>>5 = lstm l, (wg&31)*16 = dim base) ----
// flags layout: [l][group][32 wid]; hbf: [l][phase][b 0..31][512] bf16
__global__ __launch_bounds__(512) void lstm_persist(
    const float* __restrict__ Whh_q, const float* __restrict__ Whh_k,
    const float* __restrict__ pre,
    const int* __restrict__ x,
    float* __restrict__ qout, float* __restrict__ kout,
    unsigned short* __restrict__ hbf,
    unsigned int* __restrict__ flags)
{
    __shared__ unsigned short w_lds[64][512];   // 64 KB, 16B-chunk XOR swizzled
    __shared__ unsigned short h_lds[16][512];   // 16 KB, one batch-group, swizzled
    __shared__ float          g_lds[2][64][17]; // 8.7 KB, [K-half][gate-row][b_local]
    __shared__ unsigned char  x_lds[TB * TT];   // 16 KB
    __shared__ float          pre_lds[NTOK][64];// 3.5 KB, [tok][gate*16+dd]

    int wg  = blockIdx.x;
    int l   = wg >> 5;
    int wid = wg & 31;
    int d0  = wid << 4;                         // 16 dims per WG
    int tid = threadIdx.x;
    int lane = tid & 63;
    int wv = tid >> 6;                          // 8 waves
    int rt = wv & 3;                            // gate-row tile (rows rt*16..)
    int kh = wv >> 2;                           // K-half (256 each)

    const float* Whh = l ? Whh_k : Whh_q;
    float* hist = l ? kout : qout;
    unsigned short* hb_l = hbf + (size_t)l * 2 * TB * TD;
    unsigned int* fl = flags + l * 64;

    // ---- stage W slice: 64 gate-rows (gate*16+dd), f32->bf16, XOR swizzle ----
    {
        int r = tid >> 3;                       // 0..63, 8 threads/row
        const float* src = Whh + (size_t)((r >> 4) * TD + d0 + (r & 15)) * TD;
#pragma unroll
        for (int i = 0; i < 8; ++i) {
            int c = (tid & 7) + 8 * i;          // chunk 0..63 (8 bf16 = 16B)
            float4 a = ((const float4*)src)[c * 2];
            float4 b4 = ((const float4*)src)[c * 2 + 1];
            unsigned short* dst = &w_lds[r][(c ^ (r & 7)) * 8];
            dst[0] = (unsigned short)f2bf(a.x); dst[1] = (unsigned short)f2bf(a.y);
            dst[2] = (unsigned short)f2bf(a.z); dst[3] = (unsigned short)f2bf(a.w);
            dst[4] = (unsigned short)f2bf(b4.x); dst[5] = (unsigned short)f2bf(b4.y);
            dst[6] = (unsigned short)f2bf(b4.z); dst[7] = (unsigned short)f2bf(b4.w);
        }
    }
    for (int i = tid; i < TB * TT; i += 512) x_lds[i] = (unsigned char)x[i];
    for (int i = tid; i < NTOK * 64; i += 512) {
        int tok = i >> 6, j = i & 63;           // j = gate*16 + dd
        pre_lds[tok][j] = pre[((size_t)l * NTOK + tok) * (4 * TD) + (j >> 4) * TD + d0 + (j & 15)];
    }
    __syncthreads();

    int b  = tid >> 4, dd = tid & 15;           // tail mapping (b 0..31)
    float creg = 0.f;

    for (int t = 0; t < TT; ++t) {
        for (int g = 0; g < 2; ++g) {           // batch group: A (b<16), B (b>=16)
            if (t > 0) {
                // -- poll: all 32 producer WGs published group g, step t-1 --
                if (tid < 64) {
                    const unsigned int* fp = fl + g * 32 + (lane & 31);
                    for (;;) {
                        unsigned int v = load4_coh(fp);
                        if (__all((int)(v >= (unsigned int)t))) break;
                        __builtin_amdgcn_s_sleep(2);
                    }
                }
                __syncthreads();
                // -- stage h_g(t-1): 16 rows x 512 bf16 -> h_lds (deduped) --
                {
                    int row = tid >> 5;         // 0..15, 32 thr/row
                    const unsigned short* src = hb_l
                        + (size_t)(((t - 1) & 1) * TB + g * 16 + row) * TD;
                    int c0 = tid & 31, c1 = c0 + 32;
                    short8 v0 = load16_coh(src + c0 * 8);
                    short8 v1 = load16_coh(src + c1 * 8);
                    asm volatile("s_waitcnt vmcnt(0)" ::: "memory");
                    __builtin_amdgcn_sched_barrier(0);
                    *(short8*)&h_lds[row][(c0 ^ (row & 7)) * 8] = v0;
                    *(short8*)&h_lds[row][(c1 ^ (row & 7)) * 8] = v1;
                }
                __syncthreads();
                // -- MFMA: wave (rt, kh): tile [16 gate-rows x 16 b], K=256 --
                f32x4 acc = {0.f, 0.f, 0.f, 0.f};
                {
                    int rr = rt * 16 + (lane & 15);
                    int hr = lane & 15;
#pragma unroll
                    for (int j = 0; j < 8; ++j) {
                        int kk = kh * 8 + j;
                        int c = kk * 4 + (lane >> 4);
                        short8 a  = *(const short8*)&h_lds[hr][(c ^ (hr & 7)) * 8];
                        short8 bf = *(const short8*)&w_lds[rr][(c ^ (rr & 7)) * 8];
                        acc = __builtin_amdgcn_mfma_f32_16x16x32_bf16(a, bf, acc, 0, 0, 0);
                    }
                }
                {
                    int gr = rt * 16 + (lane & 15);
                    int gb = (lane >> 4) << 2;
#pragma unroll
                    for (int r2 = 0; r2 < 4; ++r2) g_lds[kh][gr][gb + r2] = acc[r2];
                }
                __syncthreads();
            }
            // -- tail: threads owning this group's batches --
            if ((b >> 4) == g) {
                int bl = b & 15;
                int tok = x_lds[b * TT + t];
                float s_i = 0.f, s_f = 0.f, s_g = 0.f, s_o = 0.f;
                if (t > 0) {
                    s_i = g_lds[0][dd][bl]      + g_lds[1][dd][bl];
                    s_f = g_lds[0][16 + dd][bl] + g_lds[1][16 + dd][bl];
                    s_g = g_lds[0][32 + dd][bl] + g_lds[1][32 + dd][bl];
                    s_o = g_lds[0][48 + dd][bl] + g_lds[1][48 + dd][bl];
                }
                float gi = s_i + pre_lds[tok][dd];
                float gf = s_f + pre_lds[tok][16 + dd];
                float gg = s_g + pre_lds[tok][32 + dd];
                float go = s_o + pre_lds[tok][48 + dd];
                float i_ = fsigmoid(gi), f_ = fsigmoid(gf), g_ = ftanh(gg), o_ = fsigmoid(go);
                creg = f_ * creg + i_ * g_;
                float h = o_ * ftanh(creg);
                hist[((size_t)b * TT + t) * TD + d0 + dd] = h;   // plain cached f32
                store2_coh(hb_l + (size_t)((t & 1) * TB + b) * TD + d0 + dd, f2bf(h));
                asm volatile("s_waitcnt vmcnt(0)" ::: "memory");  // drain before flag
            }
            __syncthreads();
            if (tid == 0) store4_coh(fl + g * 32 + wid, (unsigned int)(t + 1));
        }
    }
}

// ---- A[b] = q[b] @ k[b]^T, f32, 64x64 tile / WG, 4x4 per thread ----
__global__ __launch_bounds__(256) void qk_gemm(
    const float* __restrict__ q, const float* __restrict__ k, float* __restrict__ A)
{
    __shared__ float qs[64][68];
    __shared__ float ks[64][68];
    int b = blockIdx.y;
    int t0 = (blockIdx.x >> 3) * 64;
    int s0 = (blockIdx.x & 7) * 64;
    const float* qb = q + (size_t)b * TT * TD;
    const float* kb = k + (size_t)b * TT * TD;
    int tid = threadIdx.x;
    int ty = tid >> 4, tx = tid & 15;
    float accr[4][4] = {};
    for (int k0 = 0; k0 < TD; k0 += 64) {
        for (int i = tid; i < 64 * 16; i += 256) {
            int r = i >> 4, c4 = i & 15;
            ((float4*)&qs[r][0])[c4] = ((const float4*)(qb + (size_t)(t0 + r) * TD + k0))[c4];
            ((float4*)&ks[r][0])[c4] = ((const float4*)(kb + (size_t)(s0 + r) * TD + k0))[c4];
        }
        __syncthreads();
#pragma unroll 4
        for (int kk = 0; kk < 64; kk += 4) {
            float4 qv[4], kv[4];
#pragma unroll
            for (int i = 0; i < 4; ++i) qv[i] = *(const float4*)&qs[ty * 4 + i][kk];
#pragma unroll
            for (int j = 0; j < 4; ++j) kv[j] = *(const float4*)&ks[tx * 4 + j][kk];
#pragma unroll
            for (int i = 0; i < 4; ++i)
#pragma unroll
                for (int j = 0; j < 4; ++j)
                    accr[i][j] += qv[i].x * kv[j].x + qv[i].y * kv[j].y
                                + qv[i].z * kv[j].z + qv[i].w * kv[j].w;
        }
        __syncthreads();
    }
    for (int i = 0; i < 4; ++i)
        for (int j = 0; j < 4; ++j)
            A[(size_t)b * TT * TT + (size_t)(t0 + ty * 4 + i) * TT + (s0 + tx * 4 + j)] = accr[i][j];
}

extern "C" void kernel_launch(void* const* d_in, const int* in_sizes, int n_in,
                              void* d_out, int out_size, void* d_ws, size_t ws_size,
                              hipStream_t stream)
{
    const int*   x      = (const int*)d_in[0];
    const float* embed  = (const float*)d_in[1];
    const float* Wih_q  = (const float*)d_in[2];
    const float* Whh_q  = (const float*)d_in[3];
    const float* bih_q  = (const float*)d_in[4];
    const float* bhh_q  = (const float*)d_in[5];
    const float* Wih_k  = (const float*)d_in[6];
    const float* Whh_k  = (const float*)d_in[7];
    const float* bih_k  = (const float*)d_in[8];
    const float* bhh_k  = (const float*)d_in[9];

    float* ws   = (float*)d_ws;
    float* q    = ws;                                   // 8388608 f
    float* kbuf = q + (size_t)TB * TT * TD;             // 8388608 f
    float* pre  = kbuf + (size_t)TB * TT * TD;          // 57344 f
    unsigned short* hbf = (unsigned short*)(pre + 2 * NTOK * 4 * TD);  // 65536 us
    unsigned int* flags = (unsigned int*)(hbf + 65536); // 128 u32

    init_flags<<<1, 128, 0, stream>>>(flags);
    pre_tab_kernel<<<224, 256, 0, stream>>>(embed, Wih_q, bih_q, bhh_q,
                                            Wih_k, bih_k, bhh_k, pre);
    lstm_persist<<<64, 512, 0, stream>>>(Whh_q, Whh_k, pre, x, q, kbuf, hbf, flags);
    dim3 g(64, 32);
    qk_gemm<<<g, 256, 0, stream>>>(q, kbuf, (float*)d_out);
}